// Round 4
// baseline (116.677 us; speedup 1.0000x reference)
//
#include <hip/hip_runtime.h>

// Reduced problem: out[n] depends only on x0 = node_vec[:, :128], emb, W1_l0[:, :, :128],
// b1[:128], W2, b2, W3, b3, W4, b4.  y1/y2/gates are dead code in the reference.
//
// R3 -> R4: B-traffic/latency fix. 512 blocks x 512 threads (4 waves/SIMD),
// block = 32 nodes x 128 cols, wave = 16 nodes x 32 cols (B read once per mh-pair),
// 4-K-step register prefetch on B, even/odd-split LDS for x so no dynamic extracts.

#define NKC 64              // 2048 / 32 K-steps for 16x16x32 MFMA

typedef _Float16 h8 __attribute__((ext_vector_type(8)));
typedef _Float16 h4 __attribute__((ext_vector_type(4)));
typedef _Float16 h2 __attribute__((ext_vector_type(2)));
typedef float    f32x4 __attribute__((ext_vector_type(4)));

static __device__ __forceinline__ unsigned int pack2h(float a, float b) {
    h2 t = {(_Float16)a, (_Float16)b};
    return __builtin_bit_cast(unsigned int, t);
}
static __device__ __forceinline__ f32x4 mfma_h(uint4 a, uint4 b, f32x4 c) {
    return __builtin_amdgcn_mfma_f32_16x16x32_f16(
        __builtin_bit_cast(h8, a), __builtin_bit_cast(h8, b), c, 0, 0, 0);
}
// A-frag element j = xh * ee[j];  covers k = q*8 + j for this lane's quad
static __device__ __forceinline__ uint4 mk_afrag(_Float16 xh, const h2* ee) {
    h2 xx = {xh, xh};
    uint4 r;
    r.x = __builtin_bit_cast(unsigned int, (h2)(xx * ee[0]));
    r.y = __builtin_bit_cast(unsigned int, (h2)(xx * ee[1]));
    r.z = __builtin_bit_cast(unsigned int, (h2)(xx * ee[2]));
    r.w = __builtin_bit_cast(unsigned int, (h2)(xx * ee[3]));
    return r;
}

// ---------------------------------------------------------------------------
// Prep: W1_l0 (keep cols 0..127) and W2 -> f16 B-fragment order:
//   W1T[kc][t][lane][j] = f16(W1[K = kc*32 + (lane>>4)*8 + j][t*16 + (lane&15)])
//   W2T[kc][lane][j]    = f16(W2[K][lane&15])
// ---------------------------------------------------------------------------
__global__ __launch_bounds__(256) void prep_kernel(
        const float* __restrict__ W1, const float* __restrict__ W2,
        _Float16* __restrict__ W1T, _Float16* __restrict__ W2T) {
    const int b = blockIdx.x, kc = b >> 2, tp = b & 3;
    const int tid = threadIdx.x;
    __shared__ float l1[32 * 36];
    __shared__ float l2[32 * 20];

    {   // 32 rows x 32 cols sub-tile of W1 (cols tp*32 .. +32)
        int row = tid >> 3, c4 = tid & 7;
        float4 v = *(const float4*)(W1 + (size_t)(kc * 32 + row) * 224 + tp * 32 + c4 * 4);
        *(float4*)(l1 + row * 36 + c4 * 4) = v;
    }
    if (tp == 0 && tid < 128) {
        int row = tid >> 2, c4 = tid & 3;
        float4 v = *(const float4*)(W2 + (size_t)(kc * 32 + row) * 16 + c4 * 4);
        *(float4*)(l2 + row * 20 + c4 * 4) = v;
    }
    __syncthreads();

    if (tid < 128) {
        int tl = tid >> 6, t = tp * 2 + tl, lane = tid & 63;
        int q = lane >> 4, cc = lane & 15, colL = tl * 16 + cc;
        unsigned int w[4];
#pragma unroll
        for (int jj = 0; jj < 4; ++jj)
            w[jj] = pack2h(l1[(q * 8 + 2 * jj) * 36 + colL],
                           l1[(q * 8 + 2 * jj + 1) * 36 + colL]);
        *(uint4*)(W1T + (size_t)kc * 4096 + (t * 64 + lane) * 8) =
            make_uint4(w[0], w[1], w[2], w[3]);
    }
    if (tp == 0 && tid >= 128 && tid < 192) {
        int lane = tid - 128, q = lane >> 4, cc = lane & 15;
        unsigned int w[4];
#pragma unroll
        for (int jj = 0; jj < 4; ++jj)
            w[jj] = pack2h(l2[(q * 8 + 2 * jj) * 20 + cc],
                           l2[(q * 8 + 2 * jj + 1) * 20 + cc]);
        *(uint4*)(W2T + (size_t)kc * 512 + lane * 8) = make_uint4(w[0], w[1], w[2], w[3]);
    }
}

// ---------------------------------------------------------------------------
// Main: 32 nodes/block, 8 waves. Phase1: wave = (mh = wave>>2) x (cq = wave&3):
// 16 nodes x 32 cols, full K, 4-step B prefetch. Phase2: (mh, ks = cq):
// 16 nodes x 16 cols, K-quarter, LDS reduce. Phase3: 512 threads = 32n x 16c.
// x0/silu LDS split into even/odd k-columns (stride 72 halves = 144 B, 16B-aligned,
// bank stride 4 -> only free 2-way conflicts).
// ---------------------------------------------------------------------------
__global__ __launch_bounds__(512, 4) void main_kernel(
        const float* __restrict__ node_vec, const float* __restrict__ emb,
        const _Float16* __restrict__ W1T, const _Float16* __restrict__ W2T,
        const float* __restrict__ b1, const float* __restrict__ b2,
        const float* __restrict__ W3, const float* __restrict__ b3,
        const float* __restrict__ W4, const float* __restrict__ b4,
        float* __restrict__ out) {
    const int tid  = threadIdx.x;
    const int wave = tid >> 6, lane = tid & 63;
    const int q = lane >> 4, c = lane & 15;
    const int ih = q >> 1;            // which x-column parity this quad needs
    const int aodd = q & 1;           // which emb half this quad needs
    const int mh = wave >> 2;         // node half (phase 1 & 2)
    const int cq = wave & 3;          // col-quarter (phase 1) / K-quarter (phase 2)
    const int nodeBase = blockIdx.x * 32;

    __shared__ _Float16 x0e[32 * 72];       // x0 even k-cols, f16
    __shared__ _Float16 x0o[32 * 72];       // x0 odd  k-cols
    __shared__ _Float16 sce[32 * 72];       // silu(s0) even cols
    __shared__ _Float16 sco[32 * 72];       // silu(s0) odd cols
    __shared__ float    midp[4 * 32 * 17];  // phase-2 partials [ks][node][col]
    __shared__ float    mids[32 * 17];
    __shared__ float    w3s[256];
    __shared__ float    b3s[16];
    __shared__ float    w4s[16];
    __shared__ float    b4s[1];

    // stage x0 (cols 0..127), split even/odd
    for (int idx = tid; idx < 1024; idx += 512) {
        int row = idx >> 5, c4 = idx & 31;
        float4 v = *(const float4*)(node_vec + (size_t)(nodeBase + row) * 480 + c4 * 4);
        h2 ev = {(_Float16)v.x, (_Float16)v.z};
        h2 ov = {(_Float16)v.y, (_Float16)v.w};
        *(h2*)(x0e + row * 72 + c4 * 2) = ev;
        *(h2*)(x0o + row * 72 + c4 * 2) = ov;
    }
    if (tid < 256) w3s[tid] = W3[tid];
    if (tid < 16) { b3s[tid] = b3[tid]; w4s[tid] = W4[tid]; }
    if (tid == 0) b4s[0] = b4[0];

    // per-lane emb slice: node = nodeBase + mh*16 + c, a = aodd*8 + j
    h2 ee[4];
    {
        const float* ep = emb + (size_t)(nodeBase + mh * 16 + c) * 16 + aodd * 8;
        float4 v0 = *(const float4*)ep;
        float4 v1 = *(const float4*)(ep + 4);
        ee[0] = (h2){(_Float16)v0.x, (_Float16)v0.y};
        ee[1] = (h2){(_Float16)v0.z, (_Float16)v0.w};
        ee[2] = (h2){(_Float16)v1.x, (_Float16)v1.y};
        ee[3] = (h2){(_Float16)v1.z, (_Float16)v1.w};
    }
    __syncthreads();

    // ---------------- Phase 1: 16 nodes x 32 cols per wave, full K
    f32x4 acc0 = (f32x4){0.f, 0.f, 0.f, 0.f};
    f32x4 acc1 = (f32x4){0.f, 0.f, 0.f, 0.f};

    const uint4* bp = (const uint4*)W1T + cq * 128 + lane;  // frag(kc,t0)=bp[kc*512], t1 at +64
    const _Float16* xrow = (ih ? x0o : x0e) + (mh * 16 + c) * 72;

    uint4 B0[8], B1[8];
    h4 xa, xb;

#define LOADG(B, X, g)                                                         \
    {                                                                          \
        _Pragma("unroll")                                                      \
        for (int u = 0; u < 4; ++u) {                                          \
            B[2 * u]     = bp[(4 * (g) + u) * 512];                            \
            B[2 * u + 1] = bp[(4 * (g) + u) * 512 + 64];                       \
        }                                                                      \
        X = *(const h4*)(xrow + 4 * (g));                                      \
    }
#define DOG(B, X)                                                              \
    {                                                                          \
        _Pragma("unroll")                                                      \
        for (int u = 0; u < 4; ++u) {                                          \
            uint4 af = mk_afrag(X[u], ee);                                     \
            acc0 = mfma_h(af, B[2 * u], acc0);                                 \
            acc1 = mfma_h(af, B[2 * u + 1], acc1);                             \
        }                                                                      \
    }

    LOADG(B0, xa, 0);
    for (int it = 0; it < 8; ++it) {
        LOADG(B1, xb, 2 * it + 1);
        DOG(B0, xa);
        int g2 = (2 * it + 2) & 15;          // wraps to 0 on last iter (harmless)
        LOADG(B0, xa, g2);
        DOG(B1, xb);
    }
#undef LOADG
#undef DOG

    // epilogue: silu -> split f16 LDS.  C layout: col = c, row = q*4 + r.
    const float inv2048 = 0.022097086912079608f;   // 1/sqrt(128*16)
#pragma unroll
    for (int tt = 0; tt < 2; ++tt) {
        int t = cq * 2 + tt;
        float bb1v = b1[t * 16 + c];
        const f32x4& av = tt ? acc1 : acc0;
        _Float16* dst = (c & 1) ? sco : sce;
        int colh = t * 8 + (c >> 1);
#pragma unroll
        for (int r = 0; r < 4; ++r) {
            int node = mh * 16 + q * 4 + r;
            float s  = av[r] * inv2048 + bb1v;
            float sc = s / (1.f + __expf(-s));
            dst[node * 72 + colh] = (_Float16)sc;
        }
    }
    __syncthreads();

    // ---------------- Phase 2: (silu(s0) (x) emb) @ W2T, K-quarter per wave
    {
        const int ks = cq;
        const _Float16* srow = (ih ? sco : sce) + (mh * 16 + c) * 72 + ks * 16;
        h8 sx0 = *(const h8*)(srow);
        h8 sx1 = *(const h8*)(srow + 8);
        const uint4* b2p = (const uint4*)W2T + lane;
        f32x4 macc = (f32x4){0.f, 0.f, 0.f, 0.f};
        uint4 wb[4];
#pragma unroll
        for (int u = 0; u < 4; ++u) wb[u] = b2p[(ks * 16 + u) * 64];
#pragma unroll
        for (int k2 = 0; k2 < 16; ++k2) {
            uint4 cur = wb[k2 & 3];
            if (k2 + 4 < 16) wb[k2 & 3] = b2p[(ks * 16 + k2 + 4) * 64];
            _Float16 sv = (k2 < 8) ? sx0[k2] : sx1[k2 - 8];
            macc = mfma_h(mk_afrag(sv, ee), cur, macc);
        }
#pragma unroll
        for (int r = 0; r < 4; ++r) {
            int node = mh * 16 + q * 4 + r;
            midp[(ks * 32 + node) * 17 + c] = macc[r];
        }
    }
    __syncthreads();

    // reduce 4 K-quarters; 512 threads = 32 nodes x 16 cols
    {
        int node = tid >> 4, col = tid & 15;
        float m = midp[node * 17 + col] + midp[(32 + node) * 17 + col]
                + midp[(64 + node) * 17 + col] + midp[(96 + node) * 17 + col];
        mids[node * 17 + col] = m * inv2048 + b2[col];
    }
    __syncthreads();

    // ---------------- Phase 3: h = silu(mid@W3/4 + b3); out = h@W4/4 + b4
    {
        int n = tid >> 4, jj = tid & 15;
        float a = 0.f;
#pragma unroll
        for (int cc = 0; cc < 16; ++cc) a += mids[n * 17 + cc] * w3s[cc * 16 + jj];
        a = a * 0.25f + b3s[jj];
        float hh = a / (1.f + __expf(-a));
        float po = hh * w4s[jj];
        po += __shfl_xor(po, 1);
        po += __shfl_xor(po, 2);
        po += __shfl_xor(po, 4);
        po += __shfl_xor(po, 8);
        if (jj == 0) out[nodeBase + n] = po * 0.25f + b4s[0];
    }
}

extern "C" void kernel_launch(void* const* d_in, const int* in_sizes, int n_in,
                              void* d_out, int out_size, void* d_ws, size_t ws_size,
                              hipStream_t stream) {
    const float* node_vec = (const float*)d_in[0];
    const float* emb      = (const float*)d_in[1];
    const float* W1       = (const float*)d_in[2];
    const float* b1v      = (const float*)d_in[5];
    const float* W2       = (const float*)d_in[6];
    const float* b2v      = (const float*)d_in[7];
    const float* W3       = (const float*)d_in[8];
    const float* b3v      = (const float*)d_in[9];
    const float* W4       = (const float*)d_in[10];
    const float* b4v      = (const float*)d_in[11];

    _Float16* W1T = (_Float16*)d_ws;          // 64*4096 halves = 512 KB
    _Float16* W2T = W1T + 64 * 4096;          // 64*512  halves =  64 KB
    float* out = (float*)d_out;

    prep_kernel<<<256, 256, 0, stream>>>(W1, W2, W1T, W2T);
    main_kernel<<<512, 512, 0, stream>>>(node_vec, emb, W1T, W2T,
                                         b1v, b2v, W3, b3v, W4, b4v, out);
}

// Round 5
// 115.246 us; speedup vs baseline: 1.0124x; 1.0124x over previous
//
#include <hip/hip_runtime.h>

// Reduced problem: out[n] depends only on x0 = node_vec[:, :128], emb, W1_l0[:, :, :128],
// b1[:128], W2, b2, W3, b3, W4, b4.  y1/y2/gates are dead code in the reference.
//
// R4 -> R5: B-stream via LDS. 256 blocks x 1024 threads (16 waves, 4/SIMD).
// Double-buffered global_load_lds (16B) stages W1T chunks (2 K-steps x 128 cols
// = 16 KB) once per block; waves consume via ds_read_b128. Global B traffic
// 512 MB -> 128 MB, no per-step vmcnt in the consume path.

#define NKC 64              // 2048 / 32 K-steps for 16x16x32 MFMA

typedef _Float16 h8 __attribute__((ext_vector_type(8)));
typedef _Float16 h2 __attribute__((ext_vector_type(2)));
typedef float    f32x4 __attribute__((ext_vector_type(4)));
typedef unsigned int u32;

static __device__ __forceinline__ u32 pack2h(float a, float b) {
    h2 t = {(_Float16)a, (_Float16)b};
    return __builtin_bit_cast(u32, t);
}
static __device__ __forceinline__ f32x4 mfma_h(uint4 a, uint4 b, f32x4 c) {
    return __builtin_amdgcn_mfma_f32_16x16x32_f16(
        __builtin_bit_cast(h8, a), __builtin_bit_cast(h8, b), c, 0, 0, 0);
}
// A-frag element j = xh * ee[j];  covers k = q*8 + j for this lane's quad
static __device__ __forceinline__ uint4 mk_afrag(_Float16 xh, const h2* ee) {
    h2 xx = {xh, xh};
    uint4 r;
    r.x = __builtin_bit_cast(u32, (h2)(xx * ee[0]));
    r.y = __builtin_bit_cast(u32, (h2)(xx * ee[1]));
    r.z = __builtin_bit_cast(u32, (h2)(xx * ee[2]));
    r.w = __builtin_bit_cast(u32, (h2)(xx * ee[3]));
    return r;
}
// async 16B/lane global->LDS: g is per-lane src, l is wave-uniform LDS base
static __device__ __forceinline__ void async16(const void* g, void* l) {
    __builtin_amdgcn_global_load_lds(
        (const __attribute__((address_space(1))) u32*)g,
        (__attribute__((address_space(3))) u32*)l, 16, 0, 0);
}

// ---------------------------------------------------------------------------
// Prep: W1_l0 (keep cols 0..127) and W2 -> f16 B-fragment order:
//   W1T[kc][t][lane][j] = f16(W1[K = kc*32 + (lane>>4)*8 + j][t*16 + (lane&15)])
//   W2T[kc][lane][j]    = f16(W2[K][lane&15])
// ---------------------------------------------------------------------------
__global__ __launch_bounds__(256) void prep_kernel(
        const float* __restrict__ W1, const float* __restrict__ W2,
        _Float16* __restrict__ W1T, _Float16* __restrict__ W2T) {
    const int b = blockIdx.x, kc = b >> 2, tp = b & 3;
    const int tid = threadIdx.x;
    __shared__ float l1[32 * 36];
    __shared__ float l2[32 * 20];

    {   // 32 rows x 32 cols sub-tile of W1 (cols tp*32 .. +32)
        int row = tid >> 3, c4 = tid & 7;
        float4 v = *(const float4*)(W1 + (size_t)(kc * 32 + row) * 224 + tp * 32 + c4 * 4);
        *(float4*)(l1 + row * 36 + c4 * 4) = v;
    }
    if (tp == 0 && tid < 128) {
        int row = tid >> 2, c4 = tid & 3;
        float4 v = *(const float4*)(W2 + (size_t)(kc * 32 + row) * 16 + c4 * 4);
        *(float4*)(l2 + row * 20 + c4 * 4) = v;
    }
    __syncthreads();

    if (tid < 128) {
        int tl = tid >> 6, t = tp * 2 + tl, lane = tid & 63;
        int q = lane >> 4, cc = lane & 15, colL = tl * 16 + cc;
        u32 w[4];
#pragma unroll
        for (int jj = 0; jj < 4; ++jj)
            w[jj] = pack2h(l1[(q * 8 + 2 * jj) * 36 + colL],
                           l1[(q * 8 + 2 * jj + 1) * 36 + colL]);
        *(uint4*)(W1T + (size_t)kc * 4096 + (t * 64 + lane) * 8) =
            make_uint4(w[0], w[1], w[2], w[3]);
    }
    if (tp == 0 && tid >= 128 && tid < 192) {
        int lane = tid - 128, q = lane >> 4, cc = lane & 15;
        u32 w[4];
#pragma unroll
        for (int jj = 0; jj < 4; ++jj)
            w[jj] = pack2h(l2[(q * 8 + 2 * jj) * 20 + cc],
                           l2[(q * 8 + 2 * jj + 1) * 20 + cc]);
        *(uint4*)(W2T + (size_t)kc * 512 + lane * 8) = make_uint4(w[0], w[1], w[2], w[3]);
    }
}

// ---------------------------------------------------------------------------
// Main: 64 nodes/block, 16 waves = (g = wave>>2 node-group) x (cq = wave&3).
// Phase1: wave = 16 nodes x 32 cols, K-chunks of 2 steps staged in LDS dbuf.
// Phase2: (g, ks=cq): 16 nodes x 16 cols, K-quarter, midp reduce (overlays B buf).
// Phase3: 1024 threads = 64 nodes x 16 cols.
// LDS map (bytes): [0,32768) B dbuf | phase2+: midp [0,17408), mids [17408,21760)
//   [32768,41984) x0 even cols (later silu even) | [41984,51200) x0 odd (silu odd)
//   [51200,52224) w3s | 52224 b3s | 52288 w4s | 52352 b4s
// ---------------------------------------------------------------------------
__global__ __launch_bounds__(1024, 4) void main_kernel(
        const float* __restrict__ node_vec, const float* __restrict__ emb,
        const _Float16* __restrict__ W1T, const _Float16* __restrict__ W2T,
        const float* __restrict__ b1, const float* __restrict__ b2,
        const float* __restrict__ W3, const float* __restrict__ b3,
        const float* __restrict__ W4, const float* __restrict__ b4,
        float* __restrict__ out) {
    __shared__ __align__(16) char smem[52368];
    char*     ldsB = smem;
    _Float16* xe   = (_Float16*)(smem + 32768);
    _Float16* xo   = (_Float16*)(smem + 41984);
    float*    midp = (float*)smem;               // phase >= 2 only
    float*    mids = (float*)(smem + 17408);     // phase >= 2 only
    float*    w3s  = (float*)(smem + 51200);
    float*    b3s  = (float*)(smem + 52224);
    float*    w4s  = (float*)(smem + 52288);
    float*    b4s  = (float*)(smem + 52352);

    const int tid  = threadIdx.x;
    const int wave = tid >> 6, lane = tid & 63;
    const int q = lane >> 4, c = lane & 15;
    const int ih = q >> 1;            // x-column parity this quad needs
    const int aodd = q & 1;           // emb half this quad needs
    const int g  = wave >> 2;         // node-group
    const int cq = wave & 3;          // col-quarter (p1) / K-quarter (p2)
    const int nodeBase = blockIdx.x * 64;

    // stage x0 (cols 0..127), split even/odd k-columns, stride 72 halves
    for (int idx = tid; idx < 2048; idx += 1024) {
        int row = idx >> 5, c4 = idx & 31;
        float4 v = *(const float4*)(node_vec + (size_t)(nodeBase + row) * 480 + c4 * 4);
        h2 ev = {(_Float16)v.x, (_Float16)v.z};
        h2 ov = {(_Float16)v.y, (_Float16)v.w};
        *(h2*)(xe + row * 72 + c4 * 2) = ev;
        *(h2*)(xo + row * 72 + c4 * 2) = ov;
    }
    if (tid < 256) w3s[tid] = W3[tid];
    if (tid < 16) { b3s[tid] = b3[tid]; w4s[tid] = W4[tid]; }
    if (tid == 0) b4s[0] = b4[0];

    // per-lane emb slice: node = nodeBase + g*16 + c, a = aodd*8 + j
    h2 ee[4];
    {
        const float* ep = emb + (size_t)(nodeBase + g * 16 + c) * 16 + aodd * 8;
        float4 v0 = *(const float4*)ep;
        float4 v1 = *(const float4*)(ep + 4);
        ee[0] = (h2){(_Float16)v0.x, (_Float16)v0.y};
        ee[1] = (h2){(_Float16)v0.z, (_Float16)v0.w};
        ee[2] = (h2){(_Float16)v1.x, (_Float16)v1.y};
        ee[3] = (h2){(_Float16)v1.z, (_Float16)v1.w};
    }

    // ---------------- Phase 1: K-chunked (2 K-steps/chunk), LDS double buffer
    f32x4 acc0 = (f32x4){0.f, 0.f, 0.f, 0.f};
    f32x4 acc1 = (f32x4){0.f, 0.f, 0.f, 0.f};

    // copy role: wave w copies frag (kl = w>>3, t = w&7) of each chunk
    const int klw = wave >> 3, tw = wave & 7;
    const char* srcBase = (const char*)W1T + (size_t)((klw * 8 + tw) * 1024) + lane * 16;
    // chunk ch adds ch*2*8*1024 = ch*16384 bytes (2 K-steps of 8 frags)
    char* dstBase = ldsB + wave * 1024;          // + (ch&1)*16384

    const _Float16* xrow = (ih ? xo : xe) + (g * 16 + c) * 72;
    const int fo0 = (cq * 2) * 1024 + lane * 16;         // frag offsets in chunk
    const int fo1 = (cq * 2 + 1) * 1024 + lane * 16;

    async16(srcBase, dstBase);                   // chunk 0 -> buf 0
    __syncthreads();                             // also covers x0/emb staging

    for (int ch = 0; ch < 32; ++ch) {
        if (ch + 1 < 32)
            async16(srcBase + (size_t)(ch + 1) * 16384, dstBase + ((ch + 1) & 1) * 16384);
        const char* buf = ldsB + (ch & 1) * 16384;
        h2 xx = *(const h2*)(xrow + 2 * ch);     // x for K-steps 2ch, 2ch+1
#pragma unroll
        for (int kl = 0; kl < 2; ++kl) {
            uint4 f0 = *(const uint4*)(buf + kl * 8192 + fo0);
            uint4 f1 = *(const uint4*)(buf + kl * 8192 + fo1);
            uint4 af = mk_afrag(xx[kl], ee);
            acc0 = mfma_h(af, f0, acc0);
            acc1 = mfma_h(af, f1, acc1);
        }
        __syncthreads();   // my copy done (vmcnt drain) + all waves done with buf
    }

    // epilogue: silu -> f16 LDS, overlaying x0 (all waves past K-loop).
    // C layout: col = c, row = q*4 + r.
    const float inv2048 = 0.022097086912079608f;   // 1/sqrt(128*16)
#pragma unroll
    for (int tt = 0; tt < 2; ++tt) {
        int t = cq * 2 + tt;
        float bb1v = b1[t * 16 + c];
        const f32x4& av = tt ? acc1 : acc0;
        _Float16* dst = (c & 1) ? xo : xe;       // silu overlay, col parity c&1
        int colh = t * 8 + (c >> 1);
#pragma unroll
        for (int r = 0; r < 4; ++r) {
            int node = g * 16 + q * 4 + r;
            float s  = av[r] * inv2048 + bb1v;
            float sc = s / (1.f + __expf(-s));
            dst[node * 72 + colh] = (_Float16)sc;
        }
    }
    __syncthreads();

    // ---------------- Phase 2: (silu(s0) (x) emb) @ W2T, K-quarter per wave
    {
        const int ks = cq;
        const _Float16* srow = (ih ? xo : xe) + (g * 16 + c) * 72 + ks * 16;
        h8 sx0 = *(const h8*)(srow);
        h8 sx1 = *(const h8*)(srow + 8);
        const uint4* b2p = (const uint4*)W2T + lane;
        f32x4 macc = (f32x4){0.f, 0.f, 0.f, 0.f};
        uint4 wb[4];
#pragma unroll
        for (int u = 0; u < 4; ++u) wb[u] = b2p[(ks * 16 + u) * 64];
#pragma unroll
        for (int k2 = 0; k2 < 16; ++k2) {
            uint4 cur = wb[k2 & 3];
            if (k2 + 4 < 16) wb[k2 & 3] = b2p[(ks * 16 + k2 + 4) * 64];
            _Float16 sv = (k2 < 8) ? sx0[k2] : sx1[k2 - 8];
            macc = mfma_h(mk_afrag(sv, ee), cur, macc);
        }
#pragma unroll
        for (int r = 0; r < 4; ++r) {
            int node = g * 16 + q * 4 + r;
            midp[(ks * 64 + node) * 17 + c] = macc[r];
        }
    }
    __syncthreads();

    // reduce 4 K-quarters; 1024 threads = 64 nodes x 16 cols
    {
        int node = tid >> 4, col = tid & 15;
        float m = midp[node * 17 + col] + midp[(64 + node) * 17 + col]
                + midp[(128 + node) * 17 + col] + midp[(192 + node) * 17 + col];
        mids[node * 17 + col] = m * inv2048 + b2[col];
    }
    __syncthreads();

    // ---------------- Phase 3: h = silu(mid@W3/4 + b3); out = h@W4/4 + b4
    {
        int n = tid >> 4, jj = tid & 15;
        float a = 0.f;
#pragma unroll
        for (int cc = 0; cc < 16; ++cc) a += mids[n * 17 + cc] * w3s[cc * 16 + jj];
        a = a * 0.25f + b3s[jj];
        float hh = a / (1.f + __expf(-a));
        float po = hh * w4s[jj];
        po += __shfl_xor(po, 1);
        po += __shfl_xor(po, 2);
        po += __shfl_xor(po, 4);
        po += __shfl_xor(po, 8);
        if (jj == 0) out[nodeBase + n] = po * 0.25f + b4s[0];
    }
}

extern "C" void kernel_launch(void* const* d_in, const int* in_sizes, int n_in,
                              void* d_out, int out_size, void* d_ws, size_t ws_size,
                              hipStream_t stream) {
    const float* node_vec = (const float*)d_in[0];
    const float* emb      = (const float*)d_in[1];
    const float* W1       = (const float*)d_in[2];
    const float* b1v      = (const float*)d_in[5];
    const float* W2       = (const float*)d_in[6];
    const float* b2v      = (const float*)d_in[7];
    const float* W3       = (const float*)d_in[8];
    const float* b3v      = (const float*)d_in[9];
    const float* W4       = (const float*)d_in[10];
    const float* b4v      = (const float*)d_in[11];

    _Float16* W1T = (_Float16*)d_ws;          // 64*4096 halves = 512 KB
    _Float16* W2T = W1T + 64 * 4096;          // 64*512  halves =  64 KB
    float* out = (float*)d_out;

    prep_kernel<<<256, 256, 0, stream>>>(W1, W2, W1T, W2T);
    main_kernel<<<256, 1024, 0, stream>>>(node_vec, emb, W1T, W2T,
                                          b1v, b2v, W3, b3v, W4, b4v, out);
}

// Round 6
// 113.212 us; speedup vs baseline: 1.0306x; 1.0180x over previous
//
#include <hip/hip_runtime.h>

// Reduced problem: out[n] depends only on x0 = node_vec[:, :128], emb, W1_l0[:, :, :128],
// b1[:128], W2, b2, W3, b3, W4, b4.  y1/y2/gates are dead code in the reference.
//
// R5 -> R6: B-register reuse. 256 blocks x 512 threads (8 waves = 2/SIMD).
// Wave = 64 nodes x 16 cols: 4 A-fragments per K-step share one B-fragment from
// a depth-8 register ring (global/L2 direct, no LDS staging, no chunk barriers).
// Total B traffic 512 MB -> 128 MB; 4 MFMA per B-load.

#define NKC 64              // 2048 / 32 K-steps for 16x16x32 MFMA

typedef _Float16 h8 __attribute__((ext_vector_type(8)));
typedef _Float16 h2 __attribute__((ext_vector_type(2)));
typedef float    f32x4 __attribute__((ext_vector_type(4)));
typedef unsigned int u32;

static __device__ __forceinline__ u32 pack2h(float a, float b) {
    h2 t = {(_Float16)a, (_Float16)b};
    return __builtin_bit_cast(u32, t);
}
static __device__ __forceinline__ f32x4 mfma_h(uint4 a, uint4 b, f32x4 c) {
    return __builtin_amdgcn_mfma_f32_16x16x32_f16(
        __builtin_bit_cast(h8, a), __builtin_bit_cast(h8, b), c, 0, 0, 0);
}
// A-frag element j = xh * ee[j];  covers k = q*8 + j for this lane's quad
static __device__ __forceinline__ uint4 mk_afrag(_Float16 xh, const h2* ee) {
    h2 xx = {xh, xh};
    uint4 r;
    r.x = __builtin_bit_cast(u32, (h2)(xx * ee[0]));
    r.y = __builtin_bit_cast(u32, (h2)(xx * ee[1]));
    r.z = __builtin_bit_cast(u32, (h2)(xx * ee[2]));
    r.w = __builtin_bit_cast(u32, (h2)(xx * ee[3]));
    return r;
}

// ---------------------------------------------------------------------------
// Prep: W1_l0 (keep cols 0..127) and W2 -> f16 B-fragment order:
//   W1T[kc][t][lane][j] = f16(W1[K = kc*32 + (lane>>4)*8 + j][t*16 + (lane&15)])
//   W2T[kc][lane][j]    = f16(W2[K][lane&15])
// ---------------------------------------------------------------------------
__global__ __launch_bounds__(256) void prep_kernel(
        const float* __restrict__ W1, const float* __restrict__ W2,
        _Float16* __restrict__ W1T, _Float16* __restrict__ W2T) {
    const int b = blockIdx.x, kc = b >> 2, tp = b & 3;
    const int tid = threadIdx.x;
    __shared__ float l1[32 * 36];
    __shared__ float l2[32 * 20];

    {   // 32 rows x 32 cols sub-tile of W1 (cols tp*32 .. +32)
        int row = tid >> 3, c4 = tid & 7;
        float4 v = *(const float4*)(W1 + (size_t)(kc * 32 + row) * 224 + tp * 32 + c4 * 4);
        *(float4*)(l1 + row * 36 + c4 * 4) = v;
    }
    if (tp == 0 && tid < 128) {
        int row = tid >> 2, c4 = tid & 3;
        float4 v = *(const float4*)(W2 + (size_t)(kc * 32 + row) * 16 + c4 * 4);
        *(float4*)(l2 + row * 20 + c4 * 4) = v;
    }
    __syncthreads();

    if (tid < 128) {
        int tl = tid >> 6, t = tp * 2 + tl, lane = tid & 63;
        int q = lane >> 4, cc = lane & 15, colL = tl * 16 + cc;
        u32 w[4];
#pragma unroll
        for (int jj = 0; jj < 4; ++jj)
            w[jj] = pack2h(l1[(q * 8 + 2 * jj) * 36 + colL],
                           l1[(q * 8 + 2 * jj + 1) * 36 + colL]);
        *(uint4*)(W1T + (size_t)kc * 4096 + (t * 64 + lane) * 8) =
            make_uint4(w[0], w[1], w[2], w[3]);
    }
    if (tp == 0 && tid >= 128 && tid < 192) {
        int lane = tid - 128, q = lane >> 4, cc = lane & 15;
        u32 w[4];
#pragma unroll
        for (int jj = 0; jj < 4; ++jj)
            w[jj] = pack2h(l2[(q * 8 + 2 * jj) * 20 + cc],
                           l2[(q * 8 + 2 * jj + 1) * 20 + cc]);
        *(uint4*)(W2T + (size_t)kc * 512 + lane * 8) = make_uint4(w[0], w[1], w[2], w[3]);
    }
}

// ---------------------------------------------------------------------------
// Main: 64 nodes/block, 8 waves.
// Phase1: wave cq = col-tile (0..7); 4 node-group A-frags share each B-frag.
// Phase2: wave = (nh = wave>>2 node-half) x (ks = wave&3 K-quarter); LDS reduce.
// Phase3: 512 threads, 2 nodes each.
// ---------------------------------------------------------------------------
__global__ __launch_bounds__(512, 2) void main_kernel(
        const float* __restrict__ node_vec, const float* __restrict__ emb,
        const _Float16* __restrict__ W1T, const _Float16* __restrict__ W2T,
        const float* __restrict__ b1, const float* __restrict__ b2,
        const float* __restrict__ W3, const float* __restrict__ b3,
        const float* __restrict__ W4, const float* __restrict__ b4,
        float* __restrict__ out) {
    __shared__ _Float16 xe[64 * 72];        // x0 even k-cols (later silu even)
    __shared__ _Float16 xo[64 * 72];        // x0 odd  k-cols (later silu odd)
    __shared__ float    midp[4 * 64 * 17];  // phase-2 partials [ks][node][col]
    __shared__ float    mids[64 * 17];
    __shared__ float    w3s[256];
    __shared__ float    b3s[16];
    __shared__ float    w4s[16];
    __shared__ float    b4s[1];

    const int tid  = threadIdx.x;
    const int wave = tid >> 6, lane = tid & 63;
    const int q = lane >> 4, c = lane & 15;
    const int ih = q >> 1;            // x-column parity this quad needs
    const int aodd = q & 1;           // emb half this quad needs
    const int nodeBase = blockIdx.x * 64;

    // stage x0 (cols 0..127), split even/odd k-columns, stride 72 halves
    for (int idx = tid; idx < 2048; idx += 512) {
        int row = idx >> 5, c4 = idx & 31;
        float4 v = *(const float4*)(node_vec + (size_t)(nodeBase + row) * 480 + c4 * 4);
        h2 ev = {(_Float16)v.x, (_Float16)v.z};
        h2 ov = {(_Float16)v.y, (_Float16)v.w};
        *(h2*)(xe + row * 72 + c4 * 2) = ev;
        *(h2*)(xo + row * 72 + c4 * 2) = ov;
    }
    if (tid < 256) w3s[tid] = W3[tid];
    if (tid < 16) { b3s[tid] = b3[tid]; w4s[tid] = W4[tid]; }
    if (tid == 0) b4s[0] = b4[0];

    // per-lane emb slices for all 4 node-groups: node = nodeBase + g*16 + c
    h2 eeg[4][4];
#pragma unroll
    for (int g = 0; g < 4; ++g) {
        const float* ep = emb + (size_t)(nodeBase + g * 16 + c) * 16 + aodd * 8;
        float4 v0 = *(const float4*)ep;
        float4 v1 = *(const float4*)(ep + 4);
        eeg[g][0] = (h2){(_Float16)v0.x, (_Float16)v0.y};
        eeg[g][1] = (h2){(_Float16)v0.z, (_Float16)v0.w};
        eeg[g][2] = (h2){(_Float16)v1.x, (_Float16)v1.y};
        eeg[g][3] = (h2){(_Float16)v1.z, (_Float16)v1.w};
    }
    __syncthreads();

    // ---------------- Phase 1: 64 nodes x 16 cols per wave, full K
    f32x4 acc[4];
#pragma unroll
    for (int g = 0; g < 4; ++g) acc[g] = (f32x4){0.f, 0.f, 0.f, 0.f};

    const int t = wave;                               // col-tile 0..7
    const uint4* bp = (const uint4*)W1T + t * 64 + lane;   // frag(kc) = bp[kc*512]
    const _Float16* xbase = (ih ? xo : xe);
    const _Float16* xrow0 = xbase + (0 * 16 + c) * 72;
    const _Float16* xrow1 = xbase + (1 * 16 + c) * 72;
    const _Float16* xrow2 = xbase + (2 * 16 + c) * 72;
    const _Float16* xrow3 = xbase + (3 * 16 + c) * 72;

    uint4 ring[8];
#pragma unroll
    for (int r = 0; r < 8; ++r) ring[r] = bp[r * 512];
    h2 xh2[4];
    xh2[0] = *(const h2*)xrow0; xh2[1] = *(const h2*)xrow1;
    xh2[2] = *(const h2*)xrow2; xh2[3] = *(const h2*)xrow3;

#pragma unroll 8
    for (int kc = 0; kc < NKC; ++kc) {
        uint4 cur = ring[kc & 7];
        if (kc + 8 < NKC) ring[kc & 7] = bp[(kc + 8) * 512];
        _Float16 xv0 = xh2[0][kc & 1], xv1 = xh2[1][kc & 1];
        _Float16 xv2 = xh2[2][kc & 1], xv3 = xh2[3][kc & 1];
        if ((kc & 1) && kc + 1 < NKC) {
            int nx = kc + 1;
            xh2[0] = *(const h2*)(xrow0 + nx); xh2[1] = *(const h2*)(xrow1 + nx);
            xh2[2] = *(const h2*)(xrow2 + nx); xh2[3] = *(const h2*)(xrow3 + nx);
        }
        acc[0] = mfma_h(mk_afrag(xv0, eeg[0]), cur, acc[0]);
        acc[1] = mfma_h(mk_afrag(xv1, eeg[1]), cur, acc[1]);
        acc[2] = mfma_h(mk_afrag(xv2, eeg[2]), cur, acc[2]);
        acc[3] = mfma_h(mk_afrag(xv3, eeg[3]), cur, acc[3]);
    }

    __syncthreads();   // all waves done reading x before silu overlays it

    // epilogue: silu -> f16 LDS overlay. C layout: col = c, row = q*4 + r.
    const float inv2048 = 0.022097086912079608f;   // 1/sqrt(128*16)
    {
        float bb1v = b1[t * 16 + c];
        _Float16* dst = (c & 1) ? xo : xe;
        int colh = t * 8 + (c >> 1);
#pragma unroll
        for (int g = 0; g < 4; ++g) {
#pragma unroll
            for (int r = 0; r < 4; ++r) {
                int node = g * 16 + q * 4 + r;
                float s  = acc[g][r] * inv2048 + bb1v;
                float sc = s / (1.f + __expf(-s));
                dst[node * 72 + colh] = (_Float16)sc;
            }
        }
    }
    __syncthreads();

    // ---------------- Phase 2: (silu(s0) (x) emb) @ W2T
    // wave = (nh = wave>>2) node-half x (ks = wave&3) K-quarter
    {
        const int nh = wave >> 2, ks = wave & 3;
        const _Float16* sbase = (ih ? xo : xe);
        const _Float16* srow0 = sbase + ((nh * 2 + 0) * 16 + c) * 72 + ks * 16;
        const _Float16* srow1 = sbase + ((nh * 2 + 1) * 16 + c) * 72 + ks * 16;
        h8 s0a = *(const h8*)srow0, s0b = *(const h8*)(srow0 + 8);
        h8 s1a = *(const h8*)srow1, s1b = *(const h8*)(srow1 + 8);
        const uint4* b2p = (const uint4*)W2T + lane;
        f32x4 m0 = (f32x4){0.f, 0.f, 0.f, 0.f};
        f32x4 m1 = (f32x4){0.f, 0.f, 0.f, 0.f};
        uint4 wb[4];
#pragma unroll
        for (int u = 0; u < 4; ++u) wb[u] = b2p[(ks * 16 + u) * 64];
#pragma unroll
        for (int k2 = 0; k2 < 16; ++k2) {
            uint4 cur = wb[k2 & 3];
            if (k2 + 4 < 16) wb[k2 & 3] = b2p[(ks * 16 + k2 + 4) * 64];
            _Float16 sv0 = (k2 < 8) ? s0a[k2] : s0b[k2 - 8];
            _Float16 sv1 = (k2 < 8) ? s1a[k2] : s1b[k2 - 8];
            m0 = mfma_h(mk_afrag(sv0, eeg[nh * 2 + 0]), cur, m0);
            m1 = mfma_h(mk_afrag(sv1, eeg[nh * 2 + 1]), cur, m1);
        }
#pragma unroll
        for (int r = 0; r < 4; ++r) {
            int n0 = (nh * 2 + 0) * 16 + q * 4 + r;
            int n1 = (nh * 2 + 1) * 16 + q * 4 + r;
            midp[(ks * 64 + n0) * 17 + c] = m0[r];
            midp[(ks * 64 + n1) * 17 + c] = m1[r];
        }
    }
    __syncthreads();

    // reduce 4 K-quarters; 512 threads x 2 nodes
    {
        int n0 = tid >> 4, col = tid & 15;
#pragma unroll
        for (int half = 0; half < 2; ++half) {
            int node = n0 + half * 32;
            float m = midp[node * 17 + col] + midp[(64 + node) * 17 + col]
                    + midp[(128 + node) * 17 + col] + midp[(192 + node) * 17 + col];
            mids[node * 17 + col] = m * inv2048 + b2[col];
        }
    }
    __syncthreads();

    // ---------------- Phase 3: h = silu(mid@W3/4 + b3); out = h@W4/4 + b4
    {
        int n0 = tid >> 4, jj = tid & 15;
#pragma unroll
        for (int half = 0; half < 2; ++half) {
            int n = n0 + half * 32;
            float a = 0.f;
#pragma unroll
            for (int cc = 0; cc < 16; ++cc) a += mids[n * 17 + cc] * w3s[cc * 16 + jj];
            a = a * 0.25f + b3s[jj];
            float hh = a / (1.f + __expf(-a));
            float po = hh * w4s[jj];
            po += __shfl_xor(po, 1);
            po += __shfl_xor(po, 2);
            po += __shfl_xor(po, 4);
            po += __shfl_xor(po, 8);
            if (jj == 0) out[nodeBase + n] = po * 0.25f + b4s[0];
        }
    }
}

extern "C" void kernel_launch(void* const* d_in, const int* in_sizes, int n_in,
                              void* d_out, int out_size, void* d_ws, size_t ws_size,
                              hipStream_t stream) {
    const float* node_vec = (const float*)d_in[0];
    const float* emb      = (const float*)d_in[1];
    const float* W1       = (const float*)d_in[2];
    const float* b1v      = (const float*)d_in[5];
    const float* W2       = (const float*)d_in[6];
    const float* b2v      = (const float*)d_in[7];
    const float* W3       = (const float*)d_in[8];
    const float* b3v      = (const float*)d_in[9];
    const float* W4       = (const float*)d_in[10];
    const float* b4v      = (const float*)d_in[11];

    _Float16* W1T = (_Float16*)d_ws;          // 64*4096 halves = 512 KB
    _Float16* W2T = W1T + 64 * 4096;          // 64*512  halves =  64 KB
    float* out = (float*)d_out;

    prep_kernel<<<256, 256, 0, stream>>>(W1, W2, W1T, W2T);
    main_kernel<<<256, 512, 0, stream>>>(node_vec, emb, W1T, W2T,
                                         b1v, b2v, W3, b3v, W4, b4v, out);
}